// Round 1
// baseline (829.740 us; speedup 1.0000x reference)
//
#include <hip/hip_runtime.h>

#define N_NODES 100000
#define N_EDGES 1600000
#define IN_DIM 128
#define HID_DIM 128
#define OUT_DIM 64

// ---------------------------------------------------------------------------
// CSR build: histogram -> exclusive scan -> fill (order within node is
// atomic-nondeterministic; f32 sum-order jitter is ~ulp vs 8.7e-2 threshold)
// ---------------------------------------------------------------------------

__global__ void hist_kernel(const int* __restrict__ dst, int* __restrict__ counts) {
    int e = blockIdx.x * blockDim.x + threadIdx.x;
    if (e < N_EDGES) atomicAdd(&counts[dst[e]], 1);
}

// Single-block exclusive scan over counts[N_NODES] -> offsets[N_NODES+1],
// also zeroes cursor[]. 1024 threads = 16 waves; shuffle scan per wave.
__global__ void scan_kernel(const int* __restrict__ counts,
                            int* __restrict__ offsets,
                            int* __restrict__ cursor) {
    __shared__ int warp_sums[16];
    __shared__ int s_carry;
    const int tid  = threadIdx.x;        // 0..1023
    const int lane = tid & 63;
    const int wid  = tid >> 6;           // 0..15
    if (tid == 0) s_carry = 0;
    __syncthreads();

    for (int base = 0; base < N_NODES; base += 1024) {
        int idx = base + tid;
        int v = (idx < N_NODES) ? counts[idx] : 0;
        // inclusive scan within wave
        int s = v;
        #pragma unroll
        for (int off = 1; off < 64; off <<= 1) {
            int t = __shfl_up(s, off, 64);
            if (lane >= off) s += t;
        }
        if (lane == 63) warp_sums[wid] = s;
        __syncthreads();
        if (wid == 0) {
            int ws = (lane < 16) ? warp_sums[lane] : 0;
            #pragma unroll
            for (int off = 1; off < 16; off <<= 1) {
                int t = __shfl_up(ws, off, 64);
                if (lane >= off) ws += t;
            }
            if (lane < 16) warp_sums[lane] = ws;   // inclusive over waves
        }
        __syncthreads();
        int carry   = s_carry;
        int wprefix = (wid > 0) ? warp_sums[wid - 1] : 0;
        int excl    = carry + wprefix + (s - v);
        if (idx < N_NODES) { offsets[idx] = excl; cursor[idx] = 0; }
        __syncthreads();
        if (tid == 1023) s_carry = carry + warp_sums[15];
        __syncthreads();
    }
    if (tid == 0) offsets[N_NODES] = s_carry;      // == N_EDGES
}

__global__ void fill_kernel(const int* __restrict__ src, const int* __restrict__ dst,
                            const int* __restrict__ offsets, int* __restrict__ cursor,
                            int* __restrict__ csr_src) {
    int e = blockIdx.x * blockDim.x + threadIdx.x;
    if (e < N_EDGES) {
        int d = dst[e];
        int pos = offsets[d] + atomicAdd(&cursor[d], 1);
        csr_src[pos] = src[e];
    }
}

// ---------------------------------------------------------------------------
// Mean aggregation: one wave per node; lane owns a float2 slice of the row.
// ---------------------------------------------------------------------------
__global__ __launch_bounds__(256) void aggregate_kernel(
        const float* __restrict__ feat, const int* __restrict__ offsets,
        const int* __restrict__ csr_src, float* __restrict__ mean) {
    const int node = blockIdx.x * 4 + (threadIdx.x >> 6);
    const int lane = threadIdx.x & 63;
    if (node >= N_NODES) return;
    const int beg = offsets[node], end = offsets[node + 1];
    float ax = 0.f, ay = 0.f;
    for (int j = beg; j < end; ++j) {
        int s = csr_src[j];
        float2 v = ((const float2*)(feat + (size_t)s * IN_DIM))[lane];
        ax += v.x; ay += v.y;
    }
    float inv = (end > beg) ? 1.0f / (float)(end - beg) : 0.0f;
    ((float2*)(mean + (size_t)node * IN_DIM))[lane] = make_float2(ax * inv, ay * inv);
}

// ---------------------------------------------------------------------------
// Layer: out[n][j] = (RELU?) b[j] + sum_k mean[n][k]*Wl[k][j] + xin[n][k]*Wr[k][j]
// 256 thr = 8 slots x 32 lanes; slot stages NP=4 nodes (mean+x rows) in LDS;
// each thread keeps acc[4][NO] in registers -> 4x register reuse of W.
// ---------------------------------------------------------------------------
template <int M, bool RELU>
__global__ __launch_bounds__(256) void layer_kernel(
        const float* __restrict__ mean, const float* __restrict__ xin,
        const float* __restrict__ Wl, const float* __restrict__ Wr,
        const float* __restrict__ bias, float* __restrict__ out) {
    constexpr int TS = 32;            // threads per slot
    constexpr int SLOTS = 256 / TS;   // 8
    constexpr int NP = 4;             // nodes per slot
    constexpr int NO = M / TS;        // outputs per thread (4 or 2)
    __shared__ float s_m[SLOTS][NP][IN_DIM];
    __shared__ float s_x[SLOTS][NP][IN_DIM];

    const int t = threadIdx.x;
    const int slot = t / TS;
    const int lt = t % TS;
    const int node0 = (blockIdx.x * SLOTS + slot) * NP;   // grid exact: 3125*8*4 = 100000

    #pragma unroll
    for (int r = 0; r < NP; ++r) {
        const int n = node0 + r;
        ((float4*)s_m[slot][r])[lt] = ((const float4*)(mean + (size_t)n * IN_DIM))[lt];
        ((float4*)s_x[slot][r])[lt] = ((const float4*)(xin  + (size_t)n * IN_DIM))[lt];
    }
    __syncthreads();

    const int j = lt * NO;
    float acc[NP][NO];
    #pragma unroll
    for (int n = 0; n < NP; ++n)
        #pragma unroll
        for (int o = 0; o < NO; ++o) acc[n][o] = bias[j + o];

    for (int k4 = 0; k4 < IN_DIM; k4 += 4) {
        float4 m4[NP], x4[NP];
        #pragma unroll
        for (int n = 0; n < NP; ++n) {
            m4[n] = *(const float4*)&s_m[slot][n][k4];
            x4[n] = *(const float4*)&s_x[slot][n][k4];
        }
        #pragma unroll
        for (int kk = 0; kk < 4; ++kk) {
            const float* wlrow = Wl + (size_t)(k4 + kk) * M + j;
            const float* wrrow = Wr + (size_t)(k4 + kk) * M + j;
            float wl[NO], wr[NO];
            #pragma unroll
            for (int o = 0; o < NO; ++o) { wl[o] = wlrow[o]; wr[o] = wrrow[o]; }
            #pragma unroll
            for (int n = 0; n < NP; ++n) {
                const float mv = (kk == 0) ? m4[n].x : (kk == 1) ? m4[n].y : (kk == 2) ? m4[n].z : m4[n].w;
                const float xv = (kk == 0) ? x4[n].x : (kk == 1) ? x4[n].y : (kk == 2) ? x4[n].z : x4[n].w;
                #pragma unroll
                for (int o = 0; o < NO; ++o) acc[n][o] += mv * wl[o] + xv * wr[o];
            }
        }
    }

    #pragma unroll
    for (int n = 0; n < NP; ++n) {
        float* orow = out + (size_t)(node0 + n) * M + j;
        #pragma unroll
        for (int o = 0; o < NO; ++o) {
            float v = acc[n][o];
            if (RELU) v = fmaxf(v, 0.0f);
            orow[o] = v;
        }
    }
}

// ---------------------------------------------------------------------------

extern "C" void kernel_launch(void* const* d_in, const int* in_sizes, int n_in,
                              void* d_out, int out_size, void* d_ws, size_t ws_size,
                              hipStream_t stream) {
    const float* x    = (const float*)d_in[0];
    const int*   ei   = (const int*)d_in[1];       // [2, E] int32
    const float* W1l  = (const float*)d_in[2];
    const float* W1r  = (const float*)d_in[3];
    const float* b1   = (const float*)d_in[4];
    const float* W2l  = (const float*)d_in[5];
    const float* W2r  = (const float*)d_in[6];
    const float* b2   = (const float*)d_in[7];
    float* out = (float*)d_out;

    const int* src = ei;
    const int* dst = ei + N_EDGES;

    // workspace layout (16B-aligned regions)
    char* ws = (char*)d_ws;
    int* counts  = (int*)ws;                        // N_NODES
    int* cursor  = counts + N_NODES;                // N_NODES
    int* offsets = cursor + N_NODES;                // N_NODES + 4 (padded)
    int* csr_src = offsets + N_NODES + 4;           // N_EDGES
    float* mean1 = (float*)(csr_src + N_EDGES);     // N_NODES * IN_DIM  (reused for layer-2 mean)
    float* h     = mean1 + (size_t)N_NODES * IN_DIM;// N_NODES * HID_DIM

    hipMemsetAsync(counts, 0, N_NODES * sizeof(int), stream);

    const int eb = (N_EDGES + 255) / 256;   // 6250
    hist_kernel<<<eb, 256, 0, stream>>>(dst, counts);
    scan_kernel<<<1, 1024, 0, stream>>>(counts, offsets, cursor);
    fill_kernel<<<eb, 256, 0, stream>>>(src, dst, offsets, cursor, csr_src);

    // layer 1
    aggregate_kernel<<<N_NODES / 4, 256, 0, stream>>>(x, offsets, csr_src, mean1);
    layer_kernel<HID_DIM, true><<<N_NODES / 32, 256, 0, stream>>>(mean1, x, W1l, W1r, b1, h);

    // layer 2 (reuse mean1 buffer)
    aggregate_kernel<<<N_NODES / 4, 256, 0, stream>>>(h, offsets, csr_src, mean1);
    layer_kernel<OUT_DIM, false><<<N_NODES / 32, 256, 0, stream>>>(mean1, h, W2l, W2r, b2, out);
}

// Round 2
// 549.870 us; speedup vs baseline: 1.5090x; 1.5090x over previous
//
#include <hip/hip_runtime.h>

#define N_NODES 100000
#define N_EDGES 1600000
#define IN_DIM 128
#define HID_DIM 128
#define OUT_DIM 64

// ---------------------------------------------------------------------------
// CSR build: histogram -> multi-block exclusive scan -> fill
// (order within node is atomic-nondeterministic; f32 sum-order jitter ~ulp)
// ---------------------------------------------------------------------------

__global__ void hist_kernel(const int* __restrict__ dst, int* __restrict__ counts) {
    int e = blockIdx.x * blockDim.x + threadIdx.x;
    if (e < N_EDGES) atomicAdd(&counts[dst[e]], 1);
}

#define SCAN_B 1024
#define SCAN_NB ((N_NODES + SCAN_B - 1) / SCAN_B)   // 98

// per-block exclusive scan; block totals to blocksums
__global__ __launch_bounds__(1024) void scan1_kernel(
        const int* __restrict__ counts, int* __restrict__ offsets,
        int* __restrict__ blocksums) {
    __shared__ int wsums[16];
    const int tid = threadIdx.x, lane = tid & 63, wid = tid >> 6;
    const int idx = blockIdx.x * SCAN_B + tid;
    int v = (idx < N_NODES) ? counts[idx] : 0;
    int s = v;
    #pragma unroll
    for (int off = 1; off < 64; off <<= 1) {
        int t = __shfl_up(s, off, 64);
        if (lane >= off) s += t;
    }
    if (lane == 63) wsums[wid] = s;
    __syncthreads();
    if (wid == 0) {
        int ws = (lane < 16) ? wsums[lane] : 0;
        #pragma unroll
        for (int off = 1; off < 16; off <<= 1) {
            int t = __shfl_up(ws, off, 64);
            if (lane >= off) ws += t;
        }
        if (lane < 16) wsums[lane] = ws;
    }
    __syncthreads();
    int excl = (wid ? wsums[wid - 1] : 0) + (s - v);
    if (idx < N_NODES) offsets[idx] = excl;
    if (tid == 1023) blocksums[blockIdx.x] = wsums[15];
}

// exclusive scan of the 98 block sums (one small block)
__global__ __launch_bounds__(128) void scan2_kernel(int* __restrict__ blocksums) {
    __shared__ int w0sum;
    const int t = threadIdx.x, lane = t & 63, wid = t >> 6;
    int v = (t < SCAN_NB) ? blocksums[t] : 0;
    int s = v;
    #pragma unroll
    for (int off = 1; off < 64; off <<= 1) {
        int u = __shfl_up(s, off, 64);
        if (lane >= off) s += u;
    }
    if (t == 63) w0sum = s;
    __syncthreads();
    int excl = (s - v) + (wid ? w0sum : 0);
    if (t < SCAN_NB) blocksums[t] = excl;
}

// add block offsets, zero cursor, write sentinel
__global__ __launch_bounds__(1024) void scan3_kernel(
        int* __restrict__ offsets, const int* __restrict__ blocksums,
        int* __restrict__ cursor) {
    const int idx = blockIdx.x * SCAN_B + threadIdx.x;
    if (idx < N_NODES) {
        offsets[idx] += blocksums[blockIdx.x];
        cursor[idx] = 0;
    }
    if (idx == 0) offsets[N_NODES] = N_EDGES;
}

__global__ void fill_kernel(const int* __restrict__ src, const int* __restrict__ dst,
                            const int* __restrict__ offsets, int* __restrict__ cursor,
                            int* __restrict__ csr_src) {
    int e = blockIdx.x * blockDim.x + threadIdx.x;
    if (e < N_EDGES) {
        int d = dst[e];
        int pos = offsets[d] + atomicAdd(&cursor[d], 1);
        csr_src[pos] = src[e];
    }
}

// ---------------------------------------------------------------------------
// Mean aggregation: one wave per node; lane owns a float2 slice of the row.
// Edge loop unrolled x4 so 4 gathers are in flight per lane.
// ---------------------------------------------------------------------------
__global__ __launch_bounds__(256) void aggregate_kernel(
        const float* __restrict__ feat, const int* __restrict__ offsets,
        const int* __restrict__ csr_src, float* __restrict__ mean) {
    const int node = blockIdx.x * 4 + (threadIdx.x >> 6);
    const int lane = threadIdx.x & 63;
    const int beg = offsets[node], end = offsets[node + 1];
    float ax = 0.f, ay = 0.f;
    int j = beg;
    for (; j + 4 <= end; j += 4) {
        int s0 = csr_src[j], s1 = csr_src[j + 1], s2 = csr_src[j + 2], s3 = csr_src[j + 3];
        float2 v0 = ((const float2*)(feat + (size_t)s0 * IN_DIM))[lane];
        float2 v1 = ((const float2*)(feat + (size_t)s1 * IN_DIM))[lane];
        float2 v2 = ((const float2*)(feat + (size_t)s2 * IN_DIM))[lane];
        float2 v3 = ((const float2*)(feat + (size_t)s3 * IN_DIM))[lane];
        ax += v0.x + v1.x + v2.x + v3.x;
        ay += v0.y + v1.y + v2.y + v3.y;
    }
    for (; j < end; ++j) {
        int s = csr_src[j];
        float2 v = ((const float2*)(feat + (size_t)s * IN_DIM))[lane];
        ax += v.x; ay += v.y;
    }
    float inv = (end > beg) ? 1.0f / (float)(end - beg) : 0.0f;
    ((float2*)(mean + (size_t)node * IN_DIM))[lane] = make_float2(ax * inv, ay * inv);
}

// ---------------------------------------------------------------------------
// Layer as tiled SGEMM: C[N][M] = mean@Wl + x@Wr + b  (K = 256 = 128|128)
// Block: 128 nodes x M cols, 256 threads (tx=col-group 16, ty=node-group 16).
// Thread tile: 8 nodes x (M/16) cols, col halves at tx*4 and 64+tx*4.
// ---------------------------------------------------------------------------
template <int M, bool RELU>
__global__ __launch_bounds__(256) void layer_gemm(
        const float* __restrict__ Am, const float* __restrict__ Ax,
        const float* __restrict__ Wl, const float* __restrict__ Wr,
        const float* __restrict__ bias, float* __restrict__ out) {
    constexpr int BN = 128, BK = 16;
    constexpr int JB = M / 64;           // col-halves per thread: 2 (M=128) or 1 (M=64)
    __shared__ float As[BK][BN];
    __shared__ float Ws[BK][M];

    const int t = threadIdx.x;
    const int tx = t & 15, ty = t >> 4;
    const int n0 = blockIdx.x * BN;

    // A staging map: 4 lanes per node, each lane loads 4 consecutive k
    const int a_node = t >> 2;           // 0..63 (plus +64 second round)
    const int a_kb   = (t & 3) * 4;      // 0,4,8,12

    float acc[8][JB][4];
    #pragma unroll
    for (int b = 0; b < JB; ++b) {
        float4 bv = *(const float4*)&bias[b * 64 + tx * 4];
        #pragma unroll
        for (int n = 0; n < 8; ++n) {
            acc[n][b][0] = bv.x; acc[n][b][1] = bv.y;
            acc[n][b][2] = bv.z; acc[n][b][3] = bv.w;
        }
    }

    for (int k0 = 0; k0 < 256; k0 += BK) {
        const float* __restrict__ A = (k0 < 128) ? Am : Ax;
        const float* __restrict__ W = (k0 < 128) ? Wl : Wr;
        const int koff = k0 & 127;
        __syncthreads();
        // stage A, transposed to [k][node]
        #pragma unroll
        for (int r = 0; r < 2; ++r) {
            int nl = a_node + r * 64;
            int ng = n0 + nl; if (ng > N_NODES - 1) ng = N_NODES - 1;
            float4 v = *(const float4*)&A[(size_t)ng * 128 + koff + a_kb];
            As[a_kb + 0][nl] = v.x; As[a_kb + 1][nl] = v.y;
            As[a_kb + 2][nl] = v.z; As[a_kb + 3][nl] = v.w;
        }
        // stage W, linear copy ([BK][M] tile is contiguous in W)
        {
            const float4* srcp = (const float4*)&W[(size_t)koff * M];
            float4* dstp = (float4*)&Ws[0][0];
            #pragma unroll
            for (int r = 0; r < (BK * M) / (4 * 256); ++r)
                dstp[t + r * 256] = srcp[t + r * 256];
        }
        __syncthreads();
        #pragma unroll
        for (int kk = 0; kk < BK; ++kk) {
            float4 a0 = *(const float4*)&As[kk][ty * 8];
            float4 a1 = *(const float4*)&As[kk][ty * 8 + 4];
            float av[8] = {a0.x, a0.y, a0.z, a0.w, a1.x, a1.y, a1.z, a1.w};
            #pragma unroll
            for (int b = 0; b < JB; ++b) {
                float4 w = *(const float4*)&Ws[kk][b * 64 + tx * 4];
                #pragma unroll
                for (int n = 0; n < 8; ++n) {
                    acc[n][b][0] += av[n] * w.x;
                    acc[n][b][1] += av[n] * w.y;
                    acc[n][b][2] += av[n] * w.z;
                    acc[n][b][3] += av[n] * w.w;
                }
            }
        }
    }

    #pragma unroll
    for (int n = 0; n < 8; ++n) {
        int node = n0 + ty * 8 + n;
        if (node < N_NODES) {
            #pragma unroll
            for (int b = 0; b < JB; ++b) {
                float4 v = make_float4(acc[n][b][0], acc[n][b][1], acc[n][b][2], acc[n][b][3]);
                if (RELU) {
                    v.x = fmaxf(v.x, 0.f); v.y = fmaxf(v.y, 0.f);
                    v.z = fmaxf(v.z, 0.f); v.w = fmaxf(v.w, 0.f);
                }
                *(float4*)&out[(size_t)node * M + b * 64 + tx * 4] = v;
            }
        }
    }
}

// ---------------------------------------------------------------------------

extern "C" void kernel_launch(void* const* d_in, const int* in_sizes, int n_in,
                              void* d_out, int out_size, void* d_ws, size_t ws_size,
                              hipStream_t stream) {
    const float* x   = (const float*)d_in[0];
    const int*   ei  = (const int*)d_in[1];        // [2, E] int32
    const float* W1l = (const float*)d_in[2];
    const float* W1r = (const float*)d_in[3];
    const float* b1  = (const float*)d_in[4];
    const float* W2l = (const float*)d_in[5];
    const float* W2r = (const float*)d_in[6];
    const float* b2  = (const float*)d_in[7];
    float* out = (float*)d_out;

    const int* src = ei;
    const int* dst = ei + N_EDGES;

    // workspace layout
    char* ws = (char*)d_ws;
    int* counts    = (int*)ws;                          // N_NODES
    int* cursor    = counts + N_NODES;                  // N_NODES
    int* offsets   = cursor + N_NODES;                  // N_NODES + 4
    int* blocksums = offsets + N_NODES + 4;             // 128
    int* csr_src   = blocksums + 128;                   // N_EDGES
    float* mean1   = (float*)(csr_src + N_EDGES);       // N_NODES * IN_DIM (reused L2)
    float* h       = mean1 + (size_t)N_NODES * IN_DIM;  // N_NODES * HID_DIM

    hipMemsetAsync(counts, 0, N_NODES * sizeof(int), stream);

    const int eb = (N_EDGES + 255) / 256;   // 6250
    hist_kernel<<<eb, 256, 0, stream>>>(dst, counts);
    scan1_kernel<<<SCAN_NB, SCAN_B, 0, stream>>>(counts, offsets, blocksums);
    scan2_kernel<<<1, 128, 0, stream>>>(blocksums);
    scan3_kernel<<<SCAN_NB, SCAN_B, 0, stream>>>(offsets, blocksums, cursor);
    fill_kernel<<<eb, 256, 0, stream>>>(src, dst, offsets, cursor, csr_src);

    const int lb = (N_NODES + 127) / 128;   // 782

    // layer 1
    aggregate_kernel<<<N_NODES / 4, 256, 0, stream>>>(x, offsets, csr_src, mean1);
    layer_gemm<HID_DIM, true><<<lb, 256, 0, stream>>>(mean1, x, W1l, W1r, b1, h);

    // layer 2 (reuse mean1 buffer)
    aggregate_kernel<<<N_NODES / 4, 256, 0, stream>>>(h, offsets, csr_src, mean1);
    layer_gemm<OUT_DIM, false><<<lb, 256, 0, stream>>>(mean1, h, W2l, W2r, b2, out);
}

// Round 3
// 504.856 us; speedup vs baseline: 1.6435x; 1.0892x over previous
//
#include <hip/hip_runtime.h>

#define N_NODES 100000
#define N_EDGES 1600000
#define IN_DIM 128
#define HID_DIM 128
#define OUT_DIM 64

// ---------------------------------------------------------------------------
// bf16 helpers (RNE convert; plain bit-shift upconvert)
// ---------------------------------------------------------------------------
__device__ __forceinline__ float bf2f(unsigned short h) {
    unsigned int u = ((unsigned int)h) << 16;
    return __builtin_bit_cast(float, u);
}
__device__ __forceinline__ unsigned short f2bf(float f) {
    unsigned int u = __builtin_bit_cast(unsigned int, f);
    u += 0x7FFFu + ((u >> 16) & 1u);
    return (unsigned short)(u >> 16);
}

// ---------------------------------------------------------------------------
// CSR build: histogram -> multi-block exclusive scan -> fill
// (order within node is atomic-nondeterministic; f32 sum-order jitter ~ulp)
// ---------------------------------------------------------------------------

__global__ void hist_kernel(const int* __restrict__ dst, int* __restrict__ counts) {
    int e = blockIdx.x * blockDim.x + threadIdx.x;
    if (e < N_EDGES) atomicAdd(&counts[dst[e]], 1);
}

#define SCAN_B 1024
#define SCAN_NB ((N_NODES + SCAN_B - 1) / SCAN_B)   // 98

__global__ __launch_bounds__(1024) void scan1_kernel(
        const int* __restrict__ counts, int* __restrict__ offsets,
        int* __restrict__ blocksums) {
    __shared__ int wsums[16];
    const int tid = threadIdx.x, lane = tid & 63, wid = tid >> 6;
    const int idx = blockIdx.x * SCAN_B + tid;
    int v = (idx < N_NODES) ? counts[idx] : 0;
    int s = v;
    #pragma unroll
    for (int off = 1; off < 64; off <<= 1) {
        int t = __shfl_up(s, off, 64);
        if (lane >= off) s += t;
    }
    if (lane == 63) wsums[wid] = s;
    __syncthreads();
    if (wid == 0) {
        int ws = (lane < 16) ? wsums[lane] : 0;
        #pragma unroll
        for (int off = 1; off < 16; off <<= 1) {
            int t = __shfl_up(ws, off, 64);
            if (lane >= off) ws += t;
        }
        if (lane < 16) wsums[lane] = ws;
    }
    __syncthreads();
    int excl = (wid ? wsums[wid - 1] : 0) + (s - v);
    if (idx < N_NODES) offsets[idx] = excl;
    if (tid == 1023) blocksums[blockIdx.x] = wsums[15];
}

__global__ __launch_bounds__(128) void scan2_kernel(int* __restrict__ blocksums) {
    __shared__ int w0sum;
    const int t = threadIdx.x, lane = t & 63, wid = t >> 6;
    int v = (t < SCAN_NB) ? blocksums[t] : 0;
    int s = v;
    #pragma unroll
    for (int off = 1; off < 64; off <<= 1) {
        int u = __shfl_up(s, off, 64);
        if (lane >= off) s += u;
    }
    if (t == 63) w0sum = s;
    __syncthreads();
    int excl = (s - v) + (wid ? w0sum : 0);
    if (t < SCAN_NB) blocksums[t] = excl;
}

__global__ __launch_bounds__(1024) void scan3_kernel(
        int* __restrict__ offsets, const int* __restrict__ blocksums,
        int* __restrict__ cursor) {
    const int idx = blockIdx.x * SCAN_B + threadIdx.x;
    if (idx < N_NODES) {
        offsets[idx] += blocksums[blockIdx.x];
        cursor[idx] = 0;
    }
    if (idx == 0) offsets[N_NODES] = N_EDGES;
}

__global__ void fill_kernel(const int* __restrict__ src, const int* __restrict__ dst,
                            const int* __restrict__ offsets, int* __restrict__ cursor,
                            int* __restrict__ csr_src) {
    int e = blockIdx.x * blockDim.x + threadIdx.x;
    if (e < N_EDGES) {
        int d = dst[e];
        int pos = offsets[d] + atomicAdd(&cursor[d], 1);
        csr_src[pos] = src[e];
    }
}

// ---------------------------------------------------------------------------
// f32 -> bf16 feature conversion (streaming)
// ---------------------------------------------------------------------------
__global__ __launch_bounds__(256) void f32_to_bf16_kernel(
        const float* __restrict__ in, unsigned short* __restrict__ out, int n4) {
    int i = blockIdx.x * blockDim.x + threadIdx.x;
    if (i < n4) {
        float4 v = ((const float4*)in)[i];
        ushort4 o = make_ushort4(f2bf(v.x), f2bf(v.y), f2bf(v.z), f2bf(v.w));
        ((ushort4*)out)[i] = o;
    }
}

// ---------------------------------------------------------------------------
// Mean aggregation over bf16 features: one wave per node, 2 edges per
// iteration step (half-wave per edge: 32 lanes x ushort4 = 128 cols),
// unrolled so 8 edges are in flight. Output mean is f32.
// ---------------------------------------------------------------------------
__global__ __launch_bounds__(256) void aggregate_bf16(
        const unsigned short* __restrict__ feat, const int* __restrict__ offsets,
        const int* __restrict__ csr_src, float* __restrict__ mean) {
    const int node = blockIdx.x * 4 + (threadIdx.x >> 6);
    const int lane = threadIdx.x & 63;
    const int half = lane >> 5;          // which edge of the pair
    const int cl   = lane & 31;          // column group: cols cl*4 .. cl*4+3
    const int beg = offsets[node], end = offsets[node + 1];
    float a0 = 0.f, a1 = 0.f, a2 = 0.f, a3 = 0.f;
    int j = beg;
    for (; j + 8 <= end; j += 8) {
        #pragma unroll
        for (int u = 0; u < 4; ++u) {
            int s = csr_src[j + u * 2 + half];
            ushort4 v = ((const ushort4*)(feat + (size_t)s * 128))[cl];
            a0 += bf2f(v.x); a1 += bf2f(v.y); a2 += bf2f(v.z); a3 += bf2f(v.w);
        }
    }
    for (; j + 2 <= end; j += 2) {
        int s = csr_src[j + half];
        ushort4 v = ((const ushort4*)(feat + (size_t)s * 128))[cl];
        a0 += bf2f(v.x); a1 += bf2f(v.y); a2 += bf2f(v.z); a3 += bf2f(v.w);
    }
    if (j < end && half == 0) {
        int s = csr_src[j];
        ushort4 v = ((const ushort4*)(feat + (size_t)s * 128))[cl];
        a0 += bf2f(v.x); a1 += bf2f(v.y); a2 += bf2f(v.z); a3 += bf2f(v.w);
    }
    a0 += __shfl_down(a0, 32, 64);
    a1 += __shfl_down(a1, 32, 64);
    a2 += __shfl_down(a2, 32, 64);
    a3 += __shfl_down(a3, 32, 64);
    if (half == 0) {
        float inv = (end > beg) ? 1.0f / (float)(end - beg) : 0.0f;
        ((float4*)(mean + (size_t)node * 128))[cl] =
            make_float4(a0 * inv, a1 * inv, a2 * inv, a3 * inv);
    }
}

// ---------------------------------------------------------------------------
// Layer as tiled SGEMM: C[N][M] = Am@Wl + Ax@Wr + b  (two K=128 halves)
// Block: 128 nodes x M cols, 256 threads. Thread tile: 8 nodes x 4*(M/64).
// Ax may be bf16 (layer 2 root = hh); output may be bf16 (layer 1 -> hh).
// ---------------------------------------------------------------------------
template <int M, bool RELU, bool AX_BF16, bool OUT_BF16>
__global__ __launch_bounds__(256) void layer_gemm(
        const float* __restrict__ Am, const void* __restrict__ Axv,
        const float* __restrict__ Wl, const float* __restrict__ Wr,
        const float* __restrict__ bias, void* __restrict__ outv) {
    constexpr int BN = 128, BK = 16;
    constexpr int JB = M / 64;
    __shared__ float As[BK][BN];
    __shared__ float Ws[BK][M];

    const int t = threadIdx.x;
    const int tx = t & 15, ty = t >> 4;
    const int n0 = blockIdx.x * BN;
    const int a_node = t >> 2;           // 0..63 (+64 second round)
    const int a_kb   = (t & 3) * 4;      // 0,4,8,12

    float acc[8][JB][4];
    #pragma unroll
    for (int b = 0; b < JB; ++b) {
        float4 bv = *(const float4*)&bias[b * 64 + tx * 4];
        #pragma unroll
        for (int n = 0; n < 8; ++n) {
            acc[n][b][0] = bv.x; acc[n][b][1] = bv.y;
            acc[n][b][2] = bv.z; acc[n][b][3] = bv.w;
        }
    }

    auto stageW = [&](const float* __restrict__ W, int koff) {
        const float4* srcp = (const float4*)&W[(size_t)koff * M];
        float4* dstp = (float4*)&Ws[0][0];
        #pragma unroll
        for (int r = 0; r < (BK * M) / (4 * 256); ++r)
            dstp[t + r * 256] = srcp[t + r * 256];
    };
    auto compute = [&]() {
        #pragma unroll
        for (int kk = 0; kk < BK; ++kk) {
            float4 a0 = *(const float4*)&As[kk][ty * 8];
            float4 a1 = *(const float4*)&As[kk][ty * 8 + 4];
            float av[8] = {a0.x, a0.y, a0.z, a0.w, a1.x, a1.y, a1.z, a1.w};
            #pragma unroll
            for (int b = 0; b < JB; ++b) {
                float4 w = *(const float4*)&Ws[kk][b * 64 + tx * 4];
                #pragma unroll
                for (int n = 0; n < 8; ++n) {
                    acc[n][b][0] += av[n] * w.x;
                    acc[n][b][1] += av[n] * w.y;
                    acc[n][b][2] += av[n] * w.z;
                    acc[n][b][3] += av[n] * w.w;
                }
            }
        }
    };

    // first K-half: Am (f32) @ Wl
    for (int k0 = 0; k0 < 128; k0 += BK) {
        __syncthreads();
        #pragma unroll
        for (int r = 0; r < 2; ++r) {
            int nl = a_node + r * 64;
            int ng = n0 + nl; if (ng > N_NODES - 1) ng = N_NODES - 1;
            float4 v = *(const float4*)&Am[(size_t)ng * 128 + k0 + a_kb];
            As[a_kb + 0][nl] = v.x; As[a_kb + 1][nl] = v.y;
            As[a_kb + 2][nl] = v.z; As[a_kb + 3][nl] = v.w;
        }
        stageW(Wl, k0);
        __syncthreads();
        compute();
    }
    // second K-half: Ax (f32 or bf16) @ Wr
    for (int k0 = 0; k0 < 128; k0 += BK) {
        __syncthreads();
        #pragma unroll
        for (int r = 0; r < 2; ++r) {
            int nl = a_node + r * 64;
            int ng = n0 + nl; if (ng > N_NODES - 1) ng = N_NODES - 1;
            if constexpr (AX_BF16) {
                const unsigned short* Ax = (const unsigned short*)Axv;
                ushort4 v = *(const ushort4*)&Ax[(size_t)ng * 128 + k0 + a_kb];
                As[a_kb + 0][nl] = bf2f(v.x); As[a_kb + 1][nl] = bf2f(v.y);
                As[a_kb + 2][nl] = bf2f(v.z); As[a_kb + 3][nl] = bf2f(v.w);
            } else {
                const float* Ax = (const float*)Axv;
                float4 v = *(const float4*)&Ax[(size_t)ng * 128 + k0 + a_kb];
                As[a_kb + 0][nl] = v.x; As[a_kb + 1][nl] = v.y;
                As[a_kb + 2][nl] = v.z; As[a_kb + 3][nl] = v.w;
            }
        }
        stageW(Wr, k0);
        __syncthreads();
        compute();
    }

    #pragma unroll
    for (int n = 0; n < 8; ++n) {
        int node = n0 + ty * 8 + n;
        if (node < N_NODES) {
            #pragma unroll
            for (int b = 0; b < JB; ++b) {
                float4 v = make_float4(acc[n][b][0], acc[n][b][1], acc[n][b][2], acc[n][b][3]);
                if (RELU) {
                    v.x = fmaxf(v.x, 0.f); v.y = fmaxf(v.y, 0.f);
                    v.z = fmaxf(v.z, 0.f); v.w = fmaxf(v.w, 0.f);
                }
                if constexpr (OUT_BF16) {
                    ushort4 o = make_ushort4(f2bf(v.x), f2bf(v.y), f2bf(v.z), f2bf(v.w));
                    *(ushort4*)&((unsigned short*)outv)[(size_t)node * M + b * 64 + tx * 4] = o;
                } else {
                    *(float4*)&((float*)outv)[(size_t)node * M + b * 64 + tx * 4] = v;
                }
            }
        }
    }
}

// ---------------------------------------------------------------------------

extern "C" void kernel_launch(void* const* d_in, const int* in_sizes, int n_in,
                              void* d_out, int out_size, void* d_ws, size_t ws_size,
                              hipStream_t stream) {
    const float* x   = (const float*)d_in[0];
    const int*   ei  = (const int*)d_in[1];        // [2, E] int32
    const float* W1l = (const float*)d_in[2];
    const float* W1r = (const float*)d_in[3];
    const float* b1  = (const float*)d_in[4];
    const float* W2l = (const float*)d_in[5];
    const float* W2r = (const float*)d_in[6];
    const float* b2  = (const float*)d_in[7];
    float* out = (float*)d_out;

    const int* src = ei;
    const int* dst = ei + N_EDGES;

    // workspace layout (all regions 16B-aligned)
    char* ws = (char*)d_ws;
    int* counts    = (int*)ws;                              // 100000
    int* cursor    = counts + N_NODES;                      // 100000
    int* offsets   = cursor + N_NODES;                      // 100004
    int* blocksums = offsets + N_NODES + 4;                 // 128
    int* csr_src   = blocksums + 128;                       // 1.6M
    unsigned short* xh = (unsigned short*)(csr_src + N_EDGES);       // N*128 bf16
    unsigned short* hh = xh + (size_t)N_NODES * IN_DIM;              // N*128 bf16
    float* mean1   = (float*)(hh + (size_t)N_NODES * HID_DIM);       // N*128 f32 (both layers)

    hipMemsetAsync(counts, 0, N_NODES * sizeof(int), stream);

    const int eb = (N_EDGES + 255) / 256;   // 6250
    hist_kernel<<<eb, 256, 0, stream>>>(dst, counts);
    scan1_kernel<<<SCAN_NB, SCAN_B, 0, stream>>>(counts, offsets, blocksums);
    scan2_kernel<<<1, 128, 0, stream>>>(blocksums);
    scan3_kernel<<<SCAN_NB, SCAN_B, 0, stream>>>(offsets, blocksums, cursor);
    fill_kernel<<<eb, 256, 0, stream>>>(src, dst, offsets, cursor, csr_src);

    const int n4 = N_NODES * IN_DIM / 4;    // 3.2M float4 groups
    f32_to_bf16_kernel<<<(n4 + 255) / 256, 256, 0, stream>>>(x, xh, n4);

    const int lb = (N_NODES + 127) / 128;   // 782

    // layer 1: gather bf16 x, GEMM with f32 x root, emit h as bf16
    aggregate_bf16<<<N_NODES / 4, 256, 0, stream>>>(xh, offsets, csr_src, mean1);
    layer_gemm<HID_DIM, true, false, true><<<lb, 256, 0, stream>>>(
        mean1, x, W1l, W1r, b1, hh);

    // layer 2: gather bf16 h, GEMM with bf16 h root, emit f32 out
    aggregate_bf16<<<N_NODES / 4, 256, 0, stream>>>(hh, offsets, csr_src, mean1);
    layer_gemm<OUT_DIM, false, true, false><<<lb, 256, 0, stream>>>(
        mean1, hh, W2l, W2r, b2, out);
}

// Round 4
// 363.538 us; speedup vs baseline: 2.2824x; 1.3887x over previous
//
#include <hip/hip_runtime.h>

#define N_NODES 100000
#define N_EDGES 1600000
#define IN_DIM 128
#define HID_DIM 128
#define OUT_DIM 64

typedef __attribute__((ext_vector_type(8))) short short8;
typedef __attribute__((ext_vector_type(4))) float f32x4;

// ---------------------------------------------------------------------------
// bf16 helpers (RNE convert; bit-shift upconvert)
// ---------------------------------------------------------------------------
__device__ __forceinline__ float bf2f(unsigned short h) {
    unsigned int u = ((unsigned int)h) << 16;
    return __builtin_bit_cast(float, u);
}
__device__ __forceinline__ unsigned short f2bf(float f) {
    unsigned int u = __builtin_bit_cast(unsigned int, f);
    u += 0x7FFFu + ((u >> 16) & 1u);
    return (unsigned short)(u >> 16);
}

// ---------------------------------------------------------------------------
// CSR build: hist (atomic rank capture) -> scan -> atomic-free scatter
// ---------------------------------------------------------------------------

__global__ void hist_rank_kernel(const int* __restrict__ src, const int* __restrict__ dst,
                                 int* __restrict__ counts, unsigned* __restrict__ packed) {
    int e = blockIdx.x * blockDim.x + threadIdx.x;
    if (e < N_EDGES) {
        int d = dst[e];
        int r = atomicAdd(&counts[d], 1);          // rank of this edge within node d
        packed[e] = (unsigned)src[e] | ((unsigned)r << 17);
    }
}

#define SCAN_B 1024
#define SCAN_NB ((N_NODES + SCAN_B - 1) / SCAN_B)   // 98

__global__ __launch_bounds__(1024) void scan1_kernel(
        const int* __restrict__ counts, int* __restrict__ offsets,
        int* __restrict__ blocksums) {
    __shared__ int wsums[16];
    const int tid = threadIdx.x, lane = tid & 63, wid = tid >> 6;
    const int idx = blockIdx.x * SCAN_B + tid;
    int v = (idx < N_NODES) ? counts[idx] : 0;
    int s = v;
    #pragma unroll
    for (int off = 1; off < 64; off <<= 1) {
        int t = __shfl_up(s, off, 64);
        if (lane >= off) s += t;
    }
    if (lane == 63) wsums[wid] = s;
    __syncthreads();
    if (wid == 0) {
        int ws = (lane < 16) ? wsums[lane] : 0;
        #pragma unroll
        for (int off = 1; off < 16; off <<= 1) {
            int t = __shfl_up(ws, off, 64);
            if (lane >= off) ws += t;
        }
        if (lane < 16) wsums[lane] = ws;
    }
    __syncthreads();
    int excl = (wid ? wsums[wid - 1] : 0) + (s - v);
    if (idx < N_NODES) offsets[idx] = excl;
    if (tid == 1023) blocksums[blockIdx.x] = wsums[15];
}

__global__ __launch_bounds__(128) void scan2_kernel(int* __restrict__ blocksums) {
    __shared__ int w0sum;
    const int t = threadIdx.x, lane = t & 63, wid = t >> 6;
    int v = (t < SCAN_NB) ? blocksums[t] : 0;
    int s = v;
    #pragma unroll
    for (int off = 1; off < 64; off <<= 1) {
        int u = __shfl_up(s, off, 64);
        if (lane >= off) s += u;
    }
    if (t == 63) w0sum = s;
    __syncthreads();
    int excl = (s - v) + (wid ? w0sum : 0);
    if (t < SCAN_NB) blocksums[t] = excl;
}

__global__ __launch_bounds__(1024) void scan3_kernel(
        int* __restrict__ offsets, const int* __restrict__ blocksums) {
    const int idx = blockIdx.x * SCAN_B + threadIdx.x;
    if (idx < N_NODES) offsets[idx] += blocksums[blockIdx.x];
    if (idx == 0) offsets[N_NODES] = N_EDGES;
}

// atomic-free scatter: position = offsets[dst] + rank
__global__ void fill2_kernel(const int* __restrict__ dst, const unsigned* __restrict__ packed,
                             const int* __restrict__ offsets, int* __restrict__ csr_src) {
    int e = blockIdx.x * blockDim.x + threadIdx.x;
    if (e < N_EDGES) {
        unsigned p = packed[e];
        int d = dst[e];
        csr_src[offsets[d] + (int)(p >> 17)] = (int)(p & 0x1FFFFu);
    }
}

// ---------------------------------------------------------------------------
// f32 -> bf16 feature conversion (streaming)
// ---------------------------------------------------------------------------
__global__ __launch_bounds__(256) void f32_to_bf16_kernel(
        const float* __restrict__ in, unsigned short* __restrict__ out, int n4) {
    int i = blockIdx.x * blockDim.x + threadIdx.x;
    if (i < n4) {
        float4 v = ((const float4*)in)[i];
        ushort4 o = make_ushort4(f2bf(v.x), f2bf(v.y), f2bf(v.z), f2bf(v.w));
        ((ushort4*)out)[i] = o;
    }
}

// WT[m][k] bf16, k in [0,256): k<128 -> Wl[k][m], else Wr[k-128][m]
__global__ __launch_bounds__(256) void wt_cat_kernel(
        const float* __restrict__ Wl, const float* __restrict__ Wr,
        unsigned short* __restrict__ WT, int M) {
    int i = blockIdx.x * blockDim.x + threadIdx.x;
    if (i < M * 256) {
        int m = i >> 8, k = i & 255;
        float v = (k < 128) ? Wl[(size_t)k * M + m] : Wr[(size_t)(k - 128) * M + m];
        WT[i] = f2bf(v);
    }
}

// ---------------------------------------------------------------------------
// Mean aggregation over bf16 features: one wave per node, 4 edges per step
// (quarter-wave per edge: 16 lanes x ushort8 = 128 cols), unrolled x4 so 16
// gathers are in flight. Output mean in bf16.
// ---------------------------------------------------------------------------
__global__ __launch_bounds__(256) void aggregate_bf16(
        const unsigned short* __restrict__ feat, const int* __restrict__ offsets,
        const int* __restrict__ csr_src, unsigned short* __restrict__ mean) {
    const int node = blockIdx.x * 4 + (threadIdx.x >> 6);
    const int lane = threadIdx.x & 63;
    const int q  = lane >> 4;            // which edge of the quad
    const int cq = lane & 15;            // column group: cols cq*8 .. cq*8+7
    const int beg = offsets[node], end = offsets[node + 1];
    float a[8];
    #pragma unroll
    for (int i = 0; i < 8; ++i) a[i] = 0.f;

    int j = beg;
    for (; j + 16 <= end; j += 16) {
        #pragma unroll
        for (int u = 0; u < 4; ++u) {
            int s = csr_src[j + u * 4 + q];
            short8 v = *(const short8*)(feat + (size_t)s * 128 + cq * 8);
            #pragma unroll
            for (int i = 0; i < 8; ++i) a[i] += bf2f((unsigned short)v[i]);
        }
    }
    for (; j + 4 <= end; j += 4) {
        int s = csr_src[j + q];
        short8 v = *(const short8*)(feat + (size_t)s * 128 + cq * 8);
        #pragma unroll
        for (int i = 0; i < 8; ++i) a[i] += bf2f((unsigned short)v[i]);
    }
    const int rem = end - j;
    if (q < rem) {
        int s = csr_src[j + q];
        short8 v = *(const short8*)(feat + (size_t)s * 128 + cq * 8);
        #pragma unroll
        for (int i = 0; i < 8; ++i) a[i] += bf2f((unsigned short)v[i]);
    }
    #pragma unroll
    for (int i = 0; i < 8; ++i) {
        a[i] += __shfl_down(a[i], 32, 64);
        a[i] += __shfl_down(a[i], 16, 64);
    }
    if (q == 0) {
        float inv = (end > beg) ? 1.0f / (float)(end - beg) : 0.0f;
        short8 o;
        #pragma unroll
        for (int i = 0; i < 8; ++i) o[i] = (short)f2bf(a[i] * inv);
        *(short8*)(mean + (size_t)node * 128 + cq * 8) = o;
    }
}

// ---------------------------------------------------------------------------
// Layer GEMM via MFMA 16x16x32 bf16, no LDS.
// C[N][M] = Am@Wl + Ax@Wr + b ; A-halves bf16 [N][128]; WT[M][256] bf16.
// Block = 256 thr = 4 waves; wave owns 32 rows; frags: 2 row-tiles x M/16 col-tiles.
// A-frag: lane holds A[row= rb+(lane&15)][k = kc*32+(lane>>4)*8 +0..7] (16B load).
// B-frag: lane holds W[k][col= ct*16+(lane&15)] = WT[col][k...] (16B load).
// C/D: col = lane&15, row = (lane>>4)*4 + reg  (m89-verified).
// ---------------------------------------------------------------------------
template <int M, bool RELU, bool OUT_BF16>
__global__ __launch_bounds__(256) void layer_mfma(
        const unsigned short* __restrict__ Am, const unsigned short* __restrict__ Ax,
        const unsigned short* __restrict__ WT, const float* __restrict__ bias,
        void* __restrict__ outv) {
    constexpr int CT = M / 16;
    const int wave = threadIdx.x >> 6;
    const int lane = threadIdx.x & 63;
    const int rowbase = blockIdx.x * 128 + wave * 32;
    const int lrow = lane & 15;
    const int kq = (lane >> 4) * 8;

    f32x4 acc[2][CT];
    #pragma unroll
    for (int rt = 0; rt < 2; ++rt)
        #pragma unroll
        for (int ct = 0; ct < CT; ++ct) acc[rt][ct] = (f32x4)0.f;

    int r0 = rowbase + lrow;      if (r0 > N_NODES - 1) r0 = N_NODES - 1;
    int r1 = rowbase + 16 + lrow; if (r1 > N_NODES - 1) r1 = N_NODES - 1;

    #pragma unroll
    for (int half = 0; half < 2; ++half) {
        const unsigned short* __restrict__ A = half ? Ax : Am;
        #pragma unroll
        for (int kc = 0; kc < 4; ++kc) {
            const int kofs = kc * 32 + kq;
            short8 a0 = *(const short8*)(A + (size_t)r0 * 128 + kofs);
            short8 a1 = *(const short8*)(A + (size_t)r1 * 128 + kofs);
            #pragma unroll
            for (int ct = 0; ct < CT; ++ct) {
                short8 b = *(const short8*)(WT + (size_t)(ct * 16 + lrow) * 256
                                               + half * 128 + kc * 32 + kq);
                acc[0][ct] = __builtin_amdgcn_mfma_f32_16x16x32_bf16(a0, b, acc[0][ct], 0, 0, 0);
                acc[1][ct] = __builtin_amdgcn_mfma_f32_16x16x32_bf16(a1, b, acc[1][ct], 0, 0, 0);
            }
        }
    }

    const int colq = lane & 15;            // C col within tile
    const int rowq = (lane >> 4) * 4;      // C row group within tile
    #pragma unroll
    for (int ct = 0; ct < CT; ++ct) {
        const int col = ct * 16 + colq;
        const float bc = bias[col];
        #pragma unroll
        for (int rt = 0; rt < 2; ++rt) {
            #pragma unroll
            for (int i = 0; i < 4; ++i) {
                int row = rowbase + rt * 16 + rowq + i;
                if (row < N_NODES) {
                    float v = acc[rt][ct][i] + bc;
                    if (RELU) v = fmaxf(v, 0.f);
                    if constexpr (OUT_BF16)
                        ((unsigned short*)outv)[(size_t)row * M + col] = f2bf(v);
                    else
                        ((float*)outv)[(size_t)row * M + col] = v;
                }
            }
        }
    }
}

// ---------------------------------------------------------------------------

extern "C" void kernel_launch(void* const* d_in, const int* in_sizes, int n_in,
                              void* d_out, int out_size, void* d_ws, size_t ws_size,
                              hipStream_t stream) {
    const float* x   = (const float*)d_in[0];
    const int*   ei  = (const int*)d_in[1];        // [2, E] int32
    const float* W1l = (const float*)d_in[2];
    const float* W1r = (const float*)d_in[3];
    const float* b1  = (const float*)d_in[4];
    const float* W2l = (const float*)d_in[5];
    const float* W2r = (const float*)d_in[6];
    const float* b2  = (const float*)d_in[7];
    float* out = (float*)d_out;

    const int* src = ei;
    const int* dst = ei + N_EDGES;

    // workspace layout (all regions 16B-aligned)
    char* ws = (char*)d_ws;
    int* counts    = (int*)ws;                              // 100000
    int* offsets   = counts + N_NODES;                      // 100004
    int* blocksums = offsets + N_NODES + 4;                 // 128
    unsigned* packed = (unsigned*)(blocksums + 128);        // 1.6M
    int* csr_src   = (int*)(packed + N_EDGES);              // 1.6M
    unsigned short* xh  = (unsigned short*)(csr_src + N_EDGES);   // N*128 bf16
    unsigned short* hh  = xh + (size_t)N_NODES * 128;             // N*128 bf16
    unsigned short* mh  = hh + (size_t)N_NODES * 128;             // N*128 bf16 (mean, both layers)
    unsigned short* WT1 = mh + (size_t)N_NODES * 128;             // 128*256 bf16
    unsigned short* WT2 = WT1 + 128 * 256;                        // 64*256 bf16

    hipMemsetAsync(counts, 0, N_NODES * sizeof(int), stream);

    const int eb = (N_EDGES + 255) / 256;   // 6250
    hist_rank_kernel<<<eb, 256, 0, stream>>>(src, dst, counts, packed);
    scan1_kernel<<<SCAN_NB, SCAN_B, 0, stream>>>(counts, offsets, blocksums);
    scan2_kernel<<<1, 128, 0, stream>>>(blocksums);
    scan3_kernel<<<SCAN_NB, SCAN_B, 0, stream>>>(offsets, blocksums);
    fill2_kernel<<<eb, 256, 0, stream>>>(dst, packed, offsets, csr_src);

    const int n4 = N_NODES * IN_DIM / 4;    // 3.2M ushort4 groups
    f32_to_bf16_kernel<<<(n4 + 255) / 256, 256, 0, stream>>>(x, xh, n4);
    wt_cat_kernel<<<(128 * 256 + 255) / 256, 256, 0, stream>>>(W1l, W1r, WT1, 128);
    wt_cat_kernel<<<(64 * 256 + 255) / 256, 256, 0, stream>>>(W2l, W2r, WT2, 64);

    const int lb = (N_NODES + 127) / 128;   // 782

    // layer 1
    aggregate_bf16<<<N_NODES / 4, 256, 0, stream>>>(xh, offsets, csr_src, mh);
    layer_mfma<HID_DIM, true, true><<<lb, 256, 0, stream>>>(mh, xh, WT1, b1, hh);

    // layer 2
    aggregate_bf16<<<N_NODES / 4, 256, 0, stream>>>(hh, offsets, csr_src, mh);
    layer_mfma<OUT_DIM, false, false><<<lb, 256, 0, stream>>>(mh, hh, WT2, b2, out);
}

// Round 5
// 306.311 us; speedup vs baseline: 2.7088x; 1.1868x over previous
//
#include <hip/hip_runtime.h>

#define N_NODES 100000
#define N_EDGES 1600000
#define IN_DIM 128
#define HID_DIM 128
#define OUT_DIM 64

// dst-bucketed binning
#define BKT_SHIFT 8                      // 256 nodes per bucket
#define NPB 256                          // nodes per bucket
#define NBKT ((N_NODES + NPB - 1) / NPB) // 391
#define BKT_CAP 5120                     // mean 4092, sigma ~64 -> +16 sigma
#define BIN_CHUNK 4096                   // edges per bin block

typedef __attribute__((ext_vector_type(8))) short short8;
typedef __attribute__((ext_vector_type(4))) float f32x4;

// ---------------------------------------------------------------------------
// bf16 helpers (RNE convert; bit-shift upconvert)
// ---------------------------------------------------------------------------
__device__ __forceinline__ float bf2f(unsigned short h) {
    unsigned int u = ((unsigned int)h) << 16;
    return __builtin_bit_cast(float, u);
}
__device__ __forceinline__ unsigned short f2bf(float f) {
    unsigned int u = __builtin_bit_cast(unsigned int, f);
    u += 0x7FFFu + ((u >> 16) & 1u);
    return (unsigned short)(u >> 16);
}

// ---------------------------------------------------------------------------
// CSR build v2: fixed-capacity dst-bucket binning, bucket-local ranks.
// ---------------------------------------------------------------------------

__global__ __launch_bounds__(512) void init_cursor_kernel(int* __restrict__ cursor) {
    int t = threadIdx.x;
    if (t < NBKT) cursor[t] = t * BKT_CAP;
}

// scatter edges into bucket segments: binned[] holds (dst_local<<17)|src
__global__ __launch_bounds__(256) void bin_kernel(
        const int* __restrict__ src, const int* __restrict__ dst,
        int* __restrict__ cursor, unsigned* __restrict__ binned) {
    __shared__ int cnt[NBKT];
    __shared__ int sbase[NBKT];
    const int t = threadIdx.x;
    for (int i = t; i < NBKT; i += 256) cnt[i] = 0;
    __syncthreads();
    const int e0 = blockIdx.x * BIN_CHUNK;
    unsigned val[16];
    int bkt[16], rank[16];
    #pragma unroll
    for (int k = 0; k < 16; ++k) {
        int e = e0 + k * 256 + t;
        if (e < N_EDGES) {
            int d = dst[e];
            bkt[k] = d >> BKT_SHIFT;
            val[k] = (unsigned)src[e] | ((unsigned)(d & (NPB - 1)) << 17);
            rank[k] = atomicAdd(&cnt[bkt[k]], 1);
        } else {
            bkt[k] = -1;
        }
    }
    __syncthreads();
    for (int i = t; i < NBKT; i += 256)
        sbase[i] = cnt[i] ? atomicAdd(&cursor[i], cnt[i]) : 0;
    __syncthreads();
    #pragma unroll
    for (int k = 0; k < 16; ++k)
        if (bkt[k] >= 0) binned[(size_t)sbase[bkt[k]] + rank[k]] = val[k];
}

// exclusive scan of the 391 bucket counts -> bucketBase
__global__ __launch_bounds__(512) void bucket_scan_kernel(
        const int* __restrict__ cursor, int* __restrict__ bucketBase) {
    __shared__ int wsums[8];
    const int t = threadIdx.x, lane = t & 63, wid = t >> 6;
    int c = (t < NBKT) ? (cursor[t] - t * BKT_CAP) : 0;
    int s = c;
    #pragma unroll
    for (int off = 1; off < 64; off <<= 1) {
        int u = __shfl_up(s, off, 64);
        if (lane >= off) s += u;
    }
    if (lane == 63) wsums[wid] = s;
    __syncthreads();
    int add = 0;
    for (int w = 0; w < wid; ++w) add += wsums[w];
    s += add;
    if (t < NBKT) bucketBase[t] = s - c;
    if (t == NBKT - 1) bucketBase[NBKT] = s;   // == N_EDGES
}

// per-bucket: degree count -> local scan -> offsets (coalesced) + csr scatter
__global__ __launch_bounds__(256) void csr_kernel(
        const unsigned* __restrict__ binned, const int* __restrict__ cursor,
        const int* __restrict__ bucketBase,
        int* __restrict__ offsets, int* __restrict__ csr_src) {
    __shared__ int deg[NPB];
    __shared__ int cur[NPB];
    __shared__ int wsums[4];
    const int b = blockIdx.x, t = threadIdx.x;
    const int n0 = b << BKT_SHIFT;
    const int cnt = cursor[b] - b * BKT_CAP;
    const int base = bucketBase[b];
    const unsigned* __restrict__ ebase = binned + (size_t)b * BKT_CAP;

    deg[t] = 0;
    __syncthreads();
    for (int i = t; i < cnt; i += 256)
        atomicAdd(&deg[ebase[i] >> 17], 1);
    __syncthreads();

    // exclusive scan of deg[256]
    const int lane = t & 63, wid = t >> 6;
    int d = deg[t];
    int s = d;
    #pragma unroll
    for (int off = 1; off < 64; off <<= 1) {
        int u = __shfl_up(s, off, 64);
        if (lane >= off) s += u;
    }
    if (lane == 63) wsums[wid] = s;
    __syncthreads();
    int add = 0;
    for (int w = 0; w < wid; ++w) add += wsums[w];
    const int excl = s + add - d;
    cur[t] = excl;
    const int n = n0 + t;
    if (n <= N_NODES) offsets[n] = base + excl;  // n==N_NODES covered by last bucket
    __syncthreads();

    for (int i = t; i < cnt; i += 256) {
        unsigned v = ebase[i];
        int pos = atomicAdd(&cur[v >> 17], 1);
        csr_src[base + pos] = (int)(v & 0x1FFFFu);
    }
}

// ---------------------------------------------------------------------------
// f32 -> bf16 feature conversion (streaming)
// ---------------------------------------------------------------------------
__global__ __launch_bounds__(256) void f32_to_bf16_kernel(
        const float* __restrict__ in, unsigned short* __restrict__ out, int n4) {
    int i = blockIdx.x * blockDim.x + threadIdx.x;
    if (i < n4) {
        float4 v = ((const float4*)in)[i];
        ushort4 o = make_ushort4(f2bf(v.x), f2bf(v.y), f2bf(v.z), f2bf(v.w));
        ((ushort4*)out)[i] = o;
    }
}

// WT[m][k] bf16, k in [0,256): k<128 -> Wl[k][m], else Wr[k-128][m]
__global__ __launch_bounds__(256) void wt_cat_kernel(
        const float* __restrict__ Wl, const float* __restrict__ Wr,
        unsigned short* __restrict__ WT, int M) {
    int i = blockIdx.x * blockDim.x + threadIdx.x;
    if (i < M * 256) {
        int m = i >> 8, k = i & 255;
        float v = (k < 128) ? Wl[(size_t)k * M + m] : Wr[(size_t)(k - 128) * M + m];
        WT[i] = f2bf(v);
    }
}

// ---------------------------------------------------------------------------
// Mean aggregation over bf16 features: one wave per node, 4 edges per step
// (quarter-wave per edge: 16 lanes x ushort8 = 128 cols), 16 gathers in flight.
// ---------------------------------------------------------------------------
__global__ __launch_bounds__(256) void aggregate_bf16(
        const unsigned short* __restrict__ feat, const int* __restrict__ offsets,
        const int* __restrict__ csr_src, unsigned short* __restrict__ mean) {
    const int node = blockIdx.x * 4 + (threadIdx.x >> 6);
    const int lane = threadIdx.x & 63;
    const int q  = lane >> 4;            // which edge of the quad
    const int cq = lane & 15;            // column group: cols cq*8 .. cq*8+7
    const int beg = offsets[node], end = offsets[node + 1];
    float a[8];
    #pragma unroll
    for (int i = 0; i < 8; ++i) a[i] = 0.f;

    int j = beg;
    for (; j + 16 <= end; j += 16) {
        #pragma unroll
        for (int u = 0; u < 4; ++u) {
            int s = csr_src[j + u * 4 + q];
            short8 v = *(const short8*)(feat + (size_t)s * 128 + cq * 8);
            #pragma unroll
            for (int i = 0; i < 8; ++i) a[i] += bf2f((unsigned short)v[i]);
        }
    }
    for (; j + 4 <= end; j += 4) {
        int s = csr_src[j + q];
        short8 v = *(const short8*)(feat + (size_t)s * 128 + cq * 8);
        #pragma unroll
        for (int i = 0; i < 8; ++i) a[i] += bf2f((unsigned short)v[i]);
    }
    const int rem = end - j;
    if (q < rem) {
        int s = csr_src[j + q];
        short8 v = *(const short8*)(feat + (size_t)s * 128 + cq * 8);
        #pragma unroll
        for (int i = 0; i < 8; ++i) a[i] += bf2f((unsigned short)v[i]);
    }
    #pragma unroll
    for (int i = 0; i < 8; ++i) {
        a[i] += __shfl_down(a[i], 32, 64);
        a[i] += __shfl_down(a[i], 16, 64);
    }
    if (q == 0) {
        float inv = (end > beg) ? 1.0f / (float)(end - beg) : 0.0f;
        short8 o;
        #pragma unroll
        for (int i = 0; i < 8; ++i) o[i] = (short)f2bf(a[i] * inv);
        *(short8*)(mean + (size_t)node * 128 + cq * 8) = o;
    }
}

// ---------------------------------------------------------------------------
// Layer GEMM via MFMA 16x16x32 bf16, no LDS.
// C[N][M] = Am@Wl + Ax@Wr + b ; A-halves bf16 [N][128]; WT[M][256] bf16.
// C/D: col = lane&15, row = (lane>>4)*4 + reg  (m89-verified).
// ---------------------------------------------------------------------------
template <int M, bool RELU, bool OUT_BF16>
__global__ __launch_bounds__(256) void layer_mfma(
        const unsigned short* __restrict__ Am, const unsigned short* __restrict__ Ax,
        const unsigned short* __restrict__ WT, const float* __restrict__ bias,
        void* __restrict__ outv) {
    constexpr int CT = M / 16;
    const int wave = threadIdx.x >> 6;
    const int lane = threadIdx.x & 63;
    const int rowbase = blockIdx.x * 128 + wave * 32;
    const int lrow = lane & 15;
    const int kq = (lane >> 4) * 8;

    f32x4 acc[2][CT];
    #pragma unroll
    for (int rt = 0; rt < 2; ++rt)
        #pragma unroll
        for (int ct = 0; ct < CT; ++ct) acc[rt][ct] = (f32x4)0.f;

    int r0 = rowbase + lrow;      if (r0 > N_NODES - 1) r0 = N_NODES - 1;
    int r1 = rowbase + 16 + lrow; if (r1 > N_NODES - 1) r1 = N_NODES - 1;

    #pragma unroll
    for (int half = 0; half < 2; ++half) {
        const unsigned short* __restrict__ A = half ? Ax : Am;
        #pragma unroll
        for (int kc = 0; kc < 4; ++kc) {
            const int kofs = kc * 32 + kq;
            short8 a0 = *(const short8*)(A + (size_t)r0 * 128 + kofs);
            short8 a1 = *(const short8*)(A + (size_t)r1 * 128 + kofs);
            #pragma unroll
            for (int ct = 0; ct < CT; ++ct) {
                short8 b = *(const short8*)(WT + (size_t)(ct * 16 + lrow) * 256
                                               + half * 128 + kc * 32 + kq);
                acc[0][ct] = __builtin_amdgcn_mfma_f32_16x16x32_bf16(a0, b, acc[0][ct], 0, 0, 0);
                acc[1][ct] = __builtin_amdgcn_mfma_f32_16x16x32_bf16(a1, b, acc[1][ct], 0, 0, 0);
            }
        }
    }

    const int colq = lane & 15;
    const int rowq = (lane >> 4) * 4;
    #pragma unroll
    for (int ct = 0; ct < CT; ++ct) {
        const int col = ct * 16 + colq;
        const float bc = bias[col];
        #pragma unroll
        for (int rt = 0; rt < 2; ++rt) {
            #pragma unroll
            for (int i = 0; i < 4; ++i) {
                int row = rowbase + rt * 16 + rowq + i;
                if (row < N_NODES) {
                    float v = acc[rt][ct][i] + bc;
                    if (RELU) v = fmaxf(v, 0.f);
                    if constexpr (OUT_BF16)
                        ((unsigned short*)outv)[(size_t)row * M + col] = f2bf(v);
                    else
                        ((float*)outv)[(size_t)row * M + col] = v;
                }
            }
        }
    }
}

// ---------------------------------------------------------------------------

extern "C" void kernel_launch(void* const* d_in, const int* in_sizes, int n_in,
                              void* d_out, int out_size, void* d_ws, size_t ws_size,
                              hipStream_t stream) {
    const float* x   = (const float*)d_in[0];
    const int*   ei  = (const int*)d_in[1];        // [2, E] int32
    const float* W1l = (const float*)d_in[2];
    const float* W1r = (const float*)d_in[3];
    const float* b1  = (const float*)d_in[4];
    const float* W2l = (const float*)d_in[5];
    const float* W2r = (const float*)d_in[6];
    const float* b2  = (const float*)d_in[7];
    float* out = (float*)d_out;

    const int* src = ei;
    const int* dst = ei + N_EDGES;

    // workspace layout (16B-aligned regions)
    char* ws = (char*)d_ws;
    int* cursor     = (int*)ws;                               // 391 (+pad to 512)
    int* bucketBase = cursor + 512;                           // 392 (+pad to 512)
    int* offsets    = bucketBase + 512;                       // 100001 (+pad)
    int* csr_src    = offsets + N_NODES + 16;                 // 1.6M
    unsigned short* xh  = (unsigned short*)(csr_src + N_EDGES);   // N*128 bf16
    unsigned short* hh  = xh + (size_t)N_NODES * 128;             // N*128 bf16
    unsigned short* mh  = hh + (size_t)N_NODES * 128;             // N*128 bf16
    unsigned short* WT1 = mh + (size_t)N_NODES * 128;             // 128*256 bf16
    unsigned short* WT2 = WT1 + 128 * 256;                        // 64*256 bf16
    unsigned* binned = (unsigned*)mh;   // aliases mh; dead before agg1 writes mh

    // CSR build v2
    init_cursor_kernel<<<1, 512, 0, stream>>>(cursor);
    const int binb = (N_EDGES + BIN_CHUNK - 1) / BIN_CHUNK;   // 391
    bin_kernel<<<binb, 256, 0, stream>>>(src, dst, cursor, binned);
    bucket_scan_kernel<<<1, 512, 0, stream>>>(cursor, bucketBase);
    csr_kernel<<<NBKT, 256, 0, stream>>>(binned, cursor, bucketBase, offsets, csr_src);

    // conversions
    const int n4 = N_NODES * IN_DIM / 4;    // 3.2M
    f32_to_bf16_kernel<<<(n4 + 255) / 256, 256, 0, stream>>>(x, xh, n4);
    wt_cat_kernel<<<(128 * 256 + 255) / 256, 256, 0, stream>>>(W1l, W1r, WT1, 128);
    wt_cat_kernel<<<(64 * 256 + 255) / 256, 256, 0, stream>>>(W2l, W2r, WT2, 64);

    const int lb = (N_NODES + 127) / 128;   // 782

    // layer 1
    aggregate_bf16<<<N_NODES / 4, 256, 0, stream>>>(xh, offsets, csr_src, mh);
    layer_mfma<HID_DIM, true, true><<<lb, 256, 0, stream>>>(mh, xh, WT1, b1, hh);

    // layer 2
    aggregate_bf16<<<N_NODES / 4, 256, 0, stream>>>(hh, offsets, csr_src, mh);
    layer_mfma<OUT_DIM, false, false><<<lb, 256, 0, stream>>>(mh, hh, WT2, b2, out);
}

// Round 6
// 284.303 us; speedup vs baseline: 2.9185x; 1.0774x over previous
//
#include <hip/hip_runtime.h>

#define N_NODES 100000
#define N_EDGES 1600000
#define IN_DIM 128
#define HID_DIM 128
#define OUT_DIM 64

// dst-bucketed binning
#define BKT_SHIFT 8                      // 256 nodes per bucket
#define NPB 256                          // nodes per bucket
#define NBKT ((N_NODES + NPB - 1) / NPB) // 391
#define BKT_CAP 5120                     // mean 4092, sigma ~64 -> +16 sigma
#define BIN_CHUNK 4096                   // edges per bin block

typedef __attribute__((ext_vector_type(8))) short short8;
typedef __attribute__((ext_vector_type(4))) float f32x4;

// ---------------------------------------------------------------------------
// bf16 helpers (RNE convert; bit-shift upconvert)
// ---------------------------------------------------------------------------
__device__ __forceinline__ float bf2f(unsigned short h) {
    unsigned int u = ((unsigned int)h) << 16;
    return __builtin_bit_cast(float, u);
}
__device__ __forceinline__ unsigned short f2bf(float f) {
    unsigned int u = __builtin_bit_cast(unsigned int, f);
    u += 0x7FFFu + ((u >> 16) & 1u);
    return (unsigned short)(u >> 16);
}

// ---------------------------------------------------------------------------
// CSR build: fixed-capacity dst-bucket binning, bucket-local ranks.
// ---------------------------------------------------------------------------

__global__ __launch_bounds__(512) void init_cursor_kernel(int* __restrict__ cursor) {
    int t = threadIdx.x;
    if (t < NBKT) cursor[t] = t * BKT_CAP;
}

__global__ __launch_bounds__(256) void bin_kernel(
        const int* __restrict__ src, const int* __restrict__ dst,
        int* __restrict__ cursor, unsigned* __restrict__ binned) {
    __shared__ int cnt[NBKT];
    __shared__ int sbase[NBKT];
    const int t = threadIdx.x;
    for (int i = t; i < NBKT; i += 256) cnt[i] = 0;
    __syncthreads();
    const int e0 = blockIdx.x * BIN_CHUNK;
    unsigned val[16];
    int bkt[16], rank[16];
    #pragma unroll
    for (int k = 0; k < 16; ++k) {
        int e = e0 + k * 256 + t;
        if (e < N_EDGES) {
            int d = dst[e];
            bkt[k] = d >> BKT_SHIFT;
            val[k] = (unsigned)src[e] | ((unsigned)(d & (NPB - 1)) << 17);
            rank[k] = atomicAdd(&cnt[bkt[k]], 1);
        } else {
            bkt[k] = -1;
        }
    }
    __syncthreads();
    for (int i = t; i < NBKT; i += 256)
        sbase[i] = cnt[i] ? atomicAdd(&cursor[i], cnt[i]) : 0;
    __syncthreads();
    #pragma unroll
    for (int k = 0; k < 16; ++k)
        if (bkt[k] >= 0) binned[(size_t)sbase[bkt[k]] + rank[k]] = val[k];
}

__global__ __launch_bounds__(512) void bucket_scan_kernel(
        const int* __restrict__ cursor, int* __restrict__ bucketBase) {
    __shared__ int wsums[8];
    const int t = threadIdx.x, lane = t & 63, wid = t >> 6;
    int c = (t < NBKT) ? (cursor[t] - t * BKT_CAP) : 0;
    int s = c;
    #pragma unroll
    for (int off = 1; off < 64; off <<= 1) {
        int u = __shfl_up(s, off, 64);
        if (lane >= off) s += u;
    }
    if (lane == 63) wsums[wid] = s;
    __syncthreads();
    int add = 0;
    for (int w = 0; w < wid; ++w) add += wsums[w];
    s += add;
    if (t < NBKT) bucketBase[t] = s - c;
    if (t == NBKT - 1) bucketBase[NBKT] = s;   // == N_EDGES
}

__global__ __launch_bounds__(256) void csr_kernel(
        const unsigned* __restrict__ binned, const int* __restrict__ cursor,
        const int* __restrict__ bucketBase,
        int* __restrict__ offsets, int* __restrict__ csr_src) {
    __shared__ int deg[NPB];
    __shared__ int cur[NPB];
    __shared__ int wsums[4];
    const int b = blockIdx.x, t = threadIdx.x;
    const int n0 = b << BKT_SHIFT;
    const int cnt = cursor[b] - b * BKT_CAP;
    const int base = bucketBase[b];
    const unsigned* __restrict__ ebase = binned + (size_t)b * BKT_CAP;

    deg[t] = 0;
    __syncthreads();
    for (int i = t; i < cnt; i += 256)
        atomicAdd(&deg[ebase[i] >> 17], 1);
    __syncthreads();

    const int lane = t & 63, wid = t >> 6;
    int d = deg[t];
    int s = d;
    #pragma unroll
    for (int off = 1; off < 64; off <<= 1) {
        int u = __shfl_up(s, off, 64);
        if (lane >= off) s += u;
    }
    if (lane == 63) wsums[wid] = s;
    __syncthreads();
    int add = 0;
    for (int w = 0; w < wid; ++w) add += wsums[w];
    const int excl = s + add - d;
    cur[t] = excl;
    const int n = n0 + t;
    if (n <= N_NODES) offsets[n] = base + excl;
    __syncthreads();

    for (int i = t; i < cnt; i += 256) {
        unsigned v = ebase[i];
        int pos = atomicAdd(&cur[v >> 17], 1);
        csr_src[base + pos] = (int)(v & 0x1FFFFu);
    }
}

// ---------------------------------------------------------------------------
// f32 -> bf16 feature conversion (streaming)
// ---------------------------------------------------------------------------
__global__ __launch_bounds__(256) void f32_to_bf16_kernel(
        const float* __restrict__ in, unsigned short* __restrict__ out, int n4) {
    int i = blockIdx.x * blockDim.x + threadIdx.x;
    if (i < n4) {
        float4 v = ((const float4*)in)[i];
        ushort4 o = make_ushort4(f2bf(v.x), f2bf(v.y), f2bf(v.z), f2bf(v.w));
        ((ushort4*)out)[i] = o;
    }
}

// all weight transposes in one launch:
//   WT1[m][k], k<128 -> W1l[k][m], k>=128 -> W1r[k-128][m]   (128x256)
//   WT2l[m][k] = W2l[k][m]   (64x128)
//   WT2r[m][k] = W2r[k][m]   (64x128)
__global__ __launch_bounds__(256) void wt_all_kernel(
        const float* __restrict__ W1l, const float* __restrict__ W1r,
        const float* __restrict__ W2l, const float* __restrict__ W2r,
        unsigned short* __restrict__ WT1, unsigned short* __restrict__ WT2l,
        unsigned short* __restrict__ WT2r) {
    int i = blockIdx.x * 256 + threadIdx.x;
    if (i < 128 * 256) {
        int m = i >> 8, k = i & 255;
        float v = (k < 128) ? W1l[(size_t)k * 128 + m] : W1r[(size_t)(k - 128) * 128 + m];
        WT1[i] = f2bf(v);
        return;
    }
    i -= 128 * 256;
    if (i < 64 * 128) {
        int m = i >> 7, k = i & 127;
        WT2l[i] = f2bf(W2l[(size_t)k * 64 + m]);
        return;
    }
    i -= 64 * 128;
    if (i < 64 * 128) {
        int m = i >> 7, k = i & 127;
        WT2r[i] = f2bf(W2r[(size_t)k * 64 + m]);
    }
}

// ---------------------------------------------------------------------------
// Mean aggregation over D-dim bf16 rows, shfl-broadcast indices.
// One wave per node. LPE = D/8 lanes per edge (short8 each), EPS = 64/LPE
// edges per step. All ≤64 edge indices loaded in ONE per-lane load up front,
// broadcast via __shfl -> every feature gather is independent.
// ---------------------------------------------------------------------------
template <int D>
__global__ __launch_bounds__(256) void aggregate_sh(
        const unsigned short* __restrict__ feat, const int* __restrict__ offsets,
        const int* __restrict__ csr_src, unsigned short* __restrict__ mean) {
    constexpr int LPE = D / 8;          // 16 (D=128) or 8 (D=64)
    constexpr int EPS = 64 / LPE;       // 4 or 8
    const int node = blockIdx.x * 4 + (threadIdx.x >> 6);
    const int lane = threadIdx.x & 63;
    const int q  = lane / LPE;          // edge slot within step
    const int cq = lane % LPE;          // column group (8 cols)
    const int beg = offsets[node], end = offsets[node + 1];
    const int deg = end - beg;

    if (deg == 0) {
        if (q == 0) {
            short8 z = (short8)0;
            *(short8*)(mean + (size_t)node * D + cq * 8) = z;
        }
        return;
    }

    float a[8];
    #pragma unroll
    for (int i = 0; i < 8; ++i) a[i] = 0.f;

    const int idxv = csr_src[beg + (lane < deg ? lane : 0)];
    const int nb = deg < 64 ? deg : 64;

    #pragma unroll 4
    for (int e0 = 0; e0 < nb; e0 += EPS) {
        int ei = e0 + q;
        int s = __shfl(idxv, ei < 63 ? ei : 63, 64);
        if (ei < nb) {
            short8 v = *(const short8*)(feat + (size_t)s * D + cq * 8);
            #pragma unroll
            for (int i = 0; i < 8; ++i) a[i] += bf2f((unsigned short)v[i]);
        }
    }
    if (deg > 64) {                     // rare tail (Poisson(16) far tail)
        for (int j = beg + 64; j < end; j += EPS) {
            if (j + q < end) {
                int s = csr_src[j + q];
                short8 v = *(const short8*)(feat + (size_t)s * D + cq * 8);
                #pragma unroll
                for (int i = 0; i < 8; ++i) a[i] += bf2f((unsigned short)v[i]);
            }
        }
    }

    #pragma unroll
    for (int i = 0; i < 8; ++i) {
        #pragma unroll
        for (int off = LPE; off < 64; off <<= 1)
            a[i] += __shfl_down(a[i], off, 64);
    }

    if (q == 0) {
        float inv = 1.0f / (float)deg;
        short8 o;
        #pragma unroll
        for (int i = 0; i < 8; ++i) o[i] = (short)f2bf(a[i] * inv);
        *(short8*)(mean + (size_t)node * D + cq * 8) = o;
    }
}

// ---------------------------------------------------------------------------
// Unified MFMA GEMM: C[N][M] = A0@W(half0) [+ A1@W(half1)] [+ bias] [+ m64]
// A halves bf16 [N][128]; WT[M][KH*128] bf16. 4 waves/block, 32 rows/wave.
// C/D: col = lane&15, row = (lane>>4)*4 + reg  (m89-verified).
// ---------------------------------------------------------------------------
template <int M, int KH, bool RELU, bool OUT_BF16, bool ADD_BIAS, bool ADD_M64>
__global__ __launch_bounds__(256) void gemm_mfma(
        const unsigned short* __restrict__ A0, const unsigned short* __restrict__ A1,
        const unsigned short* __restrict__ WT, const float* __restrict__ bias,
        const unsigned short* __restrict__ m64, void* __restrict__ outv) {
    constexpr int CT = M / 16;
    constexpr int KW = KH * 128;
    const int wave = threadIdx.x >> 6;
    const int lane = threadIdx.x & 63;
    const int rowbase = blockIdx.x * 128 + wave * 32;
    const int lrow = lane & 15;
    const int kq = (lane >> 4) * 8;

    f32x4 acc[2][CT];
    #pragma unroll
    for (int rt = 0; rt < 2; ++rt)
        #pragma unroll
        for (int ct = 0; ct < CT; ++ct) acc[rt][ct] = (f32x4)0.f;

    int r0 = rowbase + lrow;      if (r0 > N_NODES - 1) r0 = N_NODES - 1;
    int r1 = rowbase + 16 + lrow; if (r1 > N_NODES - 1) r1 = N_NODES - 1;

    #pragma unroll
    for (int half = 0; half < KH; ++half) {
        const unsigned short* __restrict__ A = half ? A1 : A0;
        #pragma unroll
        for (int kc = 0; kc < 4; ++kc) {
            const int kofs = kc * 32 + kq;
            short8 a0 = *(const short8*)(A + (size_t)r0 * 128 + kofs);
            short8 a1 = *(const short8*)(A + (size_t)r1 * 128 + kofs);
            #pragma unroll
            for (int ct = 0; ct < CT; ++ct) {
                short8 b = *(const short8*)(WT + (size_t)(ct * 16 + lrow) * KW
                                               + half * 128 + kc * 32 + kq);
                acc[0][ct] = __builtin_amdgcn_mfma_f32_16x16x32_bf16(a0, b, acc[0][ct], 0, 0, 0);
                acc[1][ct] = __builtin_amdgcn_mfma_f32_16x16x32_bf16(a1, b, acc[1][ct], 0, 0, 0);
            }
        }
    }

    const int colq = lane & 15;
    const int rowq = (lane >> 4) * 4;
    #pragma unroll
    for (int ct = 0; ct < CT; ++ct) {
        const int col = ct * 16 + colq;
        float bc = 0.f;
        if constexpr (ADD_BIAS) bc = bias[col];
        #pragma unroll
        for (int rt = 0; rt < 2; ++rt) {
            #pragma unroll
            for (int i = 0; i < 4; ++i) {
                int row = rowbase + rt * 16 + rowq + i;
                if (row < N_NODES) {
                    float v = acc[rt][ct][i] + bc;
                    if constexpr (ADD_M64) v += bf2f(m64[(size_t)row * M + col]);
                    if (RELU) v = fmaxf(v, 0.f);
                    if constexpr (OUT_BF16)
                        ((unsigned short*)outv)[(size_t)row * M + col] = f2bf(v);
                    else
                        ((float*)outv)[(size_t)row * M + col] = v;
                }
            }
        }
    }
}

// ---------------------------------------------------------------------------

extern "C" void kernel_launch(void* const* d_in, const int* in_sizes, int n_in,
                              void* d_out, int out_size, void* d_ws, size_t ws_size,
                              hipStream_t stream) {
    const float* x   = (const float*)d_in[0];
    const int*   ei  = (const int*)d_in[1];        // [2, E] int32
    const float* W1l = (const float*)d_in[2];
    const float* W1r = (const float*)d_in[3];
    const float* b1  = (const float*)d_in[4];
    const float* W2l = (const float*)d_in[5];
    const float* W2r = (const float*)d_in[6];
    const float* b2  = (const float*)d_in[7];
    float* out = (float*)d_out;

    const int* src = ei;
    const int* dst = ei + N_EDGES;

    // workspace layout (16B-aligned regions)
    char* ws = (char*)d_ws;
    int* cursor     = (int*)ws;                               // 512
    int* bucketBase = cursor + 512;                           // 512
    int* offsets    = bucketBase + 512;                       // 100001 (+pad)
    int* csr_src    = offsets + N_NODES + 16;                 // 1.6M + 64 pad
    unsigned short* xh   = (unsigned short*)(csr_src + N_EDGES + 64); // N*128 bf16
    unsigned short* hh   = xh + (size_t)N_NODES * 128;                // N*128 bf16
    unsigned short* mh   = hh + (size_t)N_NODES * 128;                // N*128 bf16
    unsigned short* zh   = mh + (size_t)N_NODES * 128;                // N*64 bf16
    unsigned short* m64  = zh + (size_t)N_NODES * 64;                 // N*64 bf16
    unsigned short* WT1  = m64 + (size_t)N_NODES * 64;                // 128*256
    unsigned short* WT2l = WT1 + 128 * 256;                           // 64*128
    unsigned short* WT2r = WT2l + 64 * 128;                           // 64*128
    unsigned* binned = (unsigned*)mh;   // aliases mh; dead before agg1 writes mh

    // CSR build
    init_cursor_kernel<<<1, 512, 0, stream>>>(cursor);
    const int binb = (N_EDGES + BIN_CHUNK - 1) / BIN_CHUNK;   // 391
    bin_kernel<<<binb, 256, 0, stream>>>(src, dst, cursor, binned);
    bucket_scan_kernel<<<1, 512, 0, stream>>>(cursor, bucketBase);
    csr_kernel<<<NBKT, 256, 0, stream>>>(binned, cursor, bucketBase, offsets, csr_src);

    // conversions
    const int n4 = N_NODES * IN_DIM / 4;
    f32_to_bf16_kernel<<<(n4 + 255) / 256, 256, 0, stream>>>(x, xh, n4);
    wt_all_kernel<<<(128 * 256 + 64 * 128 * 2 + 255) / 256, 256, 0, stream>>>(
        W1l, W1r, W2l, W2r, WT1, WT2l, WT2r);

    const int lb = (N_NODES + 127) / 128;   // 782

    // layer 1: mean(x) -> mh ; h = relu(mh@W1l + x@W1r + b1) -> hh (bf16)
    aggregate_sh<128><<<N_NODES / 4, 256, 0, stream>>>(xh, offsets, csr_src, mh);
    gemm_mfma<HID_DIM, 2, true, true, true, false><<<lb, 256, 0, stream>>>(
        mh, xh, WT1, b1, nullptr, hh);

    // layer 2 (commuted): z = h@W2l -> zh ; m64 = mean(z) ; out = m64 + h@W2r + b2
    gemm_mfma<OUT_DIM, 1, false, true, false, false><<<lb, 256, 0, stream>>>(
        hh, nullptr, WT2l, nullptr, nullptr, zh);
    aggregate_sh<64><<<N_NODES / 4, 256, 0, stream>>>(zh, offsets, csr_src, m64);
    gemm_mfma<OUT_DIM, 1, false, false, true, true><<<lb, 256, 0, stream>>>(
        hh, nullptr, WT2r, b2, m64, out);
}